// Round 6
// baseline (134.988 us; speedup 1.0000x reference)
//
#include <hip/hip_runtime.h>

// Problem constants (from reference)
#define B_ 32
#define C_ 32
#define T_ 8192
#define N_ 256
#define P_ 6
#define TV_ (T_ - P_ + 1)   // valid conv length = 8187

// =============================================================================
// MEASUREMENT ROUND: round-5 kernels VERBATIM; k_final launched 3x (idempotent)
// so  dur_r6 - dur_r5 = 2 * t(k_final)  gives the exact k_final duration that
// the rocprof top-5 (monopolized by 1GB harness poison fills) cannot show.
// =============================================================================

// ---------------------------------------------------------------------------
// Kernel 0: discretize patterns -> pre-derived byte-SIMD match tables.
// Layout tabs[n][12]: dwords 0..5 = xs[p] (XOR splat), 6..11 = om[p] (mask).
// ---------------------------------------------------------------------------
__global__ void k_disc(const float* __restrict__ pat, unsigned* __restrict__ tabs) {
    int tid = blockIdx.x * blockDim.x + threadIdx.x;
    if (tid >= P_ * N_) return;
    int p = tid / N_;
    int n = tid - p * N_;
    float maxv = -3.402823466e+38f;
    float sum = 0.0f;
    unsigned mask = 0u;
    #pragma unroll
    for (int c = 0; c < C_; ++c) {
        float v = pat[((size_t)c * P_ + p) * N_ + n];
        sum += v;
        if (v > maxv) { maxv = v; mask = (1u << c); }
        else if (v == maxv) { mask |= (1u << c); }
    }
    if (!(sum > 0.0f)) mask = 0u;
    int pc = __popc(mask);
    unsigned req = (unsigned)(__ffs((int)mask) - 1);
    unsigned xs = (pc == 1) ? req * 0x01010101u : 0x7F7F7F7Fu;
    unsigned om = (pc == 0) ? 0u : 0x80808080u;
    tabs[n * 12 + p]     = xs;
    tabs[n * 12 + 6 + p] = om;
}

// ---------------------------------------------------------------------------
// Kernel 1: decode one-hot input (B,C,T,1) -> chars[B][T] (u8 packed in u32).
// ---------------------------------------------------------------------------
__global__ void k_chars(const float* __restrict__ inp, unsigned* __restrict__ chars32) {
    int bx = blockIdx.x;                  // [0, B * T/1024)
    int b  = bx >> 3;                     // T/1024 = 8 chunks per batch
    int t  = ((bx & 7) << 10) + (threadIdx.x << 2);
    const float* base = inp + (size_t)b * C_ * T_ + t;
    float ax = 0.f, ay = 0.f, az = 0.f, aw = 0.f;
    #pragma unroll
    for (int c = 0; c < C_; ++c) {
        float4 v = *(const float4*)(base + (size_t)c * T_);
        float fc = (float)c;
        ax += fc * v.x; ay += fc * v.y; az += fc * v.z; aw += fc * v.w;
    }
    unsigned w = ((unsigned)(ax + 0.5f))
               | ((unsigned)(ay + 0.5f) << 8)
               | ((unsigned)(az + 0.5f) << 16)
               | ((unsigned)(aw + 0.5f) << 24);
    chars32[((size_t)b * T_ + t) >> 2] = w;
}

// ---------------------------------------------------------------------------
// Kernel 2: verbatim round-5 k_final (68.6us total config). Idempotent.
// ---------------------------------------------------------------------------
__global__ void k_final(const unsigned char* __restrict__ chars,
                        const unsigned* __restrict__ tabs,
                        float* __restrict__ out) {
    __shared__ unsigned s32[258];         // 1024 chars + 8 halo bytes
    int tc  = blockIdx.x;                 // 0..7
    int ng  = blockIdx.y;                 // 0..7  (group of 32 n)
    int b   = blockIdx.z;                 // 0..31
    int tid = threadIdx.x;
    int t0  = tc << 10;
    int tb  = t0 + (tid << 2);

    const unsigned* csrc = (const unsigned*)(chars + (size_t)b * T_ + t0);
    s32[tid] = csrc[tid];
    if (tid < 2) {
        unsigned v = 0u;
        int gt = t0 + 1024 + tid * 4;     // byte index into chars[b][*]
        if (gt < T_) v = csrc[256 + tid];
        s32[256 + tid] = v;
    }
    __syncthreads();

    unsigned w0 = s32[tid], w1 = s32[tid + 1], w2 = s32[tid + 2];
    unsigned cw0 = w0;
    unsigned cw1 = __builtin_amdgcn_alignbyte(w1, w0, 1);
    unsigned cw2 = __builtin_amdgcn_alignbyte(w1, w0, 2);
    unsigned cw3 = __builtin_amdgcn_alignbyte(w1, w0, 3);
    unsigned cw4 = w1;
    unsigned cw5 = __builtin_amdgcn_alignbyte(w2, w1, 1);

    int n0 = ng << 5;
    const uint4* tp = (const uint4*)tabs + (size_t)n0 * 3;
    float* obase = out + ((size_t)(b * N_ + n0)) * T_ + tb;
    bool tail = (tc == 7) && (tb + 3 >= TV_);

    #pragma unroll 4
    for (int g = 0; g < 32; ++g) {
        uint4 A = tp[g * 3 + 0];          // xs0..xs3
        uint4 Bv = tp[g * 3 + 1];         // xs4, xs5, om0, om1
        uint4 Cv = tp[g * 3 + 2];         // om2..om5

        unsigned orv;
        orv  = ((cw0 ^ A.x)  + 0x7F7F7F7FU) & Bv.z;
        orv |= ((cw1 ^ A.y)  + 0x7F7F7F7FU) & Bv.w;   // v_and_or_b32
        orv |= ((cw2 ^ A.z)  + 0x7F7F7F7FU) & Cv.x;
        orv |= ((cw3 ^ A.w)  + 0x7F7F7F7FU) & Cv.y;
        orv |= ((cw4 ^ Bv.x) + 0x7F7F7F7FU) & Cv.z;
        orv |= ((cw5 ^ Bv.y) + 0x7F7F7F7FU) & Cv.w;

        float res[4];
        #pragma unroll
        for (int j = 0; j < 4; ++j)
            res[j] = (orv & (0x80u << (8 * j))) ? 0.0f : 1.0f;

        if (tail) {                       // only last chunk's tail lanes
            unsigned act = Bv.z | Bv.w | Cv.x | Cv.y | Cv.z | Cv.w;
            float padf = (act == 0u) ? 1.0f : 0.0f;  // psum==0: pad matches
            #pragma unroll
            for (int j = 0; j < 4; ++j)
                if (tb + j >= TV_) res[j] = padf;
        }

        float4 r; r.x = res[0]; r.y = res[1]; r.z = res[2]; r.w = res[3];
        *(float4*)(obase + (size_t)g * T_) = r;
    }
}

// ---------------------------------------------------------------------------
extern "C" void kernel_launch(void* const* d_in, const int* in_sizes, int n_in,
                              void* d_out, int out_size, void* d_ws, size_t ws_size,
                              hipStream_t stream) {
    const float* input_   = (const float*)d_in[0];   // (B,C,T,1) one-hot fp32
    const float* patterns = (const float*)d_in[1];   // (C,P,1,N) fp32
    float* out = (float*)d_out;                      // (B,N,T,1) fp32

    // ws layout: [0, 12288) tabs (N*12 u32); [16384, 16384+256K) chars u8
    unsigned*      tabs  = (unsigned*)d_ws;
    unsigned char* chars = (unsigned char*)d_ws + 16384;

    hipLaunchKernelGGL(k_disc, dim3((P_ * N_ + 255) / 256), dim3(256), 0, stream,
                       patterns, tabs);
    hipLaunchKernelGGL(k_chars, dim3(B_ * (T_ / 1024)), dim3(256), 0, stream,
                       input_, (unsigned*)chars);
    // k_final 3x: idempotent duplicate launches -> dur_r6 - dur_r5 = 2*t(k_final)
    hipLaunchKernelGGL(k_final, dim3(T_ / 1024, N_ / 32, B_), dim3(256), 0, stream,
                       chars, tabs, out);
    hipLaunchKernelGGL(k_final, dim3(T_ / 1024, N_ / 32, B_), dim3(256), 0, stream,
                       chars, tabs, out);
    hipLaunchKernelGGL(k_final, dim3(T_ / 1024, N_ / 32, B_), dim3(256), 0, stream,
                       chars, tabs, out);
}

// Round 7
// 110.402 us; speedup vs baseline: 1.2227x; 1.2227x over previous
//
#include <hip/hip_runtime.h>

// Problem constants (from reference)
#define B_ 32
#define C_ 32
#define T_ 8192
#define N_ 256
#define P_ 6
#define TV_ (T_ - P_ + 1)   // valid conv length = 8187

// ---------------------------------------------------------------------------
// Kernel 0 (verbatim r5): discretize patterns -> byte-SIMD match tables.
// tabs[n][12]: dwords 0..5 = xs[p] (XOR splat), 6..11 = om[p] (active mask).
//   pc==0 (col sum<=0): don't-care -> om=0
//   pc==1 (unique argmax): xs=req*0x01010101, om=0x80808080
//   pc>=2 (tie): never matches   -> xs=0x7F7F7F7F, om=0x80808080
// ---------------------------------------------------------------------------
__global__ void k_disc(const float* __restrict__ pat, unsigned* __restrict__ tabs) {
    int tid = blockIdx.x * blockDim.x + threadIdx.x;
    if (tid >= P_ * N_) return;
    int p = tid / N_;
    int n = tid - p * N_;
    float maxv = -3.402823466e+38f;
    float sum = 0.0f;
    unsigned mask = 0u;
    #pragma unroll
    for (int c = 0; c < C_; ++c) {
        float v = pat[((size_t)c * P_ + p) * N_ + n];
        sum += v;
        if (v > maxv) { maxv = v; mask = (1u << c); }
        else if (v == maxv) { mask |= (1u << c); }
    }
    if (!(sum > 0.0f)) mask = 0u;
    int pc = __popc(mask);
    unsigned req = (unsigned)(__ffs((int)mask) - 1);
    unsigned xs = (pc == 1) ? req * 0x01010101u : 0x7F7F7F7Fu;
    unsigned om = (pc == 0) ? 0u : 0x80808080u;
    tabs[n * 12 + p]     = xs;
    tabs[n * 12 + 6 + p] = om;
}

// ---------------------------------------------------------------------------
// k_mega: ONE block per (t-chunk, b) decodes its own chars chunk (phase 1)
// then runs the r5-proven n-loop over ALL 256 n (phase 2). Eliminates the
// chars global buffer, the k_chars launch, and one inter-kernel gap.
// Grid (8, 32) = 256 blocks x 256 threads (4 waves/CU; fill kernels prove
// stores saturate at ~3.3 waves/CU).
// ---------------------------------------------------------------------------
__global__ void k_mega(const float* __restrict__ inp,
                       const unsigned* __restrict__ tabs,
                       float* __restrict__ out) {
    __shared__ unsigned s32[258];         // 1024 chars + 8 halo bytes
    int tc  = blockIdx.x;                 // 0..7
    int b   = blockIdx.y;                 // 0..31
    int tid = threadIdx.x;
    int t0  = tc << 10;
    int tb  = t0 + (tid << 2);

    // ---- phase 1: one-hot decode, 4 consecutive t per thread -> LDS ----
    {
        const float* base = inp + (size_t)b * C_ * T_ + tb;
        float ax = 0.f, ay = 0.f, az = 0.f, aw = 0.f;
        #pragma unroll
        for (int c = 0; c < C_; ++c) {
            float4 v = *(const float4*)(base + (size_t)c * T_);
            float fc = (float)c;
            ax += fc * v.x; ay += fc * v.y; az += fc * v.z; aw += fc * v.w;
        }
        s32[tid] = ((unsigned)(ax + 0.5f))
                 | ((unsigned)(ay + 0.5f) << 8)
                 | ((unsigned)(az + 0.5f) << 16)
                 | ((unsigned)(aw + 0.5f) << 24);
        if (tid < 2) {                    // 8 halo t's (t0+1024 .. t0+1031)
            unsigned w = 0u;
            if (tc < 7) {                 // tc==7: halo OOB, pad region anyway
                const float* hb = inp + (size_t)b * C_ * T_ + (t0 + 1024 + (tid << 2));
                float hx = 0.f, hy = 0.f, hz = 0.f, hw = 0.f;
                #pragma unroll
                for (int c = 0; c < C_; ++c) {
                    float4 v = *(const float4*)(hb + (size_t)c * T_);
                    float fc = (float)c;
                    hx += fc * v.x; hy += fc * v.y; hz += fc * v.z; hw += fc * v.w;
                }
                w = ((unsigned)(hx + 0.5f))
                  | ((unsigned)(hy + 0.5f) << 8)
                  | ((unsigned)(hz + 0.5f) << 16)
                  | ((unsigned)(hw + 0.5f) << 24);
            }
            s32[256 + tid] = w;
        }
    }
    __syncthreads();

    // ---- phase 2: verbatim r5 match loop, now over all 256 n ----
    unsigned w0 = s32[tid], w1 = s32[tid + 1], w2 = s32[tid + 2];
    unsigned cw0 = w0;
    unsigned cw1 = __builtin_amdgcn_alignbyte(w1, w0, 1);
    unsigned cw2 = __builtin_amdgcn_alignbyte(w1, w0, 2);
    unsigned cw3 = __builtin_amdgcn_alignbyte(w1, w0, 3);
    unsigned cw4 = w1;
    unsigned cw5 = __builtin_amdgcn_alignbyte(w2, w1, 1);

    const uint4* tp = (const uint4*)tabs;
    float* obase = out + (size_t)b * N_ * T_ + tb;
    bool tail = (tc == 7) && (tb + 3 >= TV_);

    #pragma unroll 4
    for (int g = 0; g < N_; ++g) {
        uint4 A  = tp[g * 3 + 0];         // xs0..xs3   (uniform -> s_load)
        uint4 Bv = tp[g * 3 + 1];         // xs4, xs5, om0, om1
        uint4 Cv = tp[g * 3 + 2];         // om2..om5

        unsigned orv;
        orv  = ((cw0 ^ A.x)  + 0x7F7F7F7FU) & Bv.z;
        orv |= ((cw1 ^ A.y)  + 0x7F7F7F7FU) & Bv.w;   // v_and_or_b32
        orv |= ((cw2 ^ A.z)  + 0x7F7F7F7FU) & Cv.x;
        orv |= ((cw3 ^ A.w)  + 0x7F7F7F7FU) & Cv.y;
        orv |= ((cw4 ^ Bv.x) + 0x7F7F7F7FU) & Cv.z;
        orv |= ((cw5 ^ Bv.y) + 0x7F7F7F7FU) & Cv.w;

        float res[4];
        #pragma unroll
        for (int j = 0; j < 4; ++j)
            res[j] = (orv & (0x80u << (8 * j))) ? 0.0f : 1.0f;

        if (tail) {                       // only last chunk's tail lanes
            unsigned act = Bv.z | Bv.w | Cv.x | Cv.y | Cv.z | Cv.w;
            float padf = (act == 0u) ? 1.0f : 0.0f;  // psum==0: pad matches
            #pragma unroll
            for (int j = 0; j < 4; ++j)
                if (tb + j >= TV_) res[j] = padf;
        }

        float4 r; r.x = res[0]; r.y = res[1]; r.z = res[2]; r.w = res[3];
        *(float4*)(obase + (size_t)g * T_) = r;
    }
}

// ---------------------------------------------------------------------------
extern "C" void kernel_launch(void* const* d_in, const int* in_sizes, int n_in,
                              void* d_out, int out_size, void* d_ws, size_t ws_size,
                              hipStream_t stream) {
    const float* input_   = (const float*)d_in[0];   // (B,C,T,1) one-hot fp32
    const float* patterns = (const float*)d_in[1];   // (C,P,1,N) fp32
    float* out = (float*)d_out;                      // (B,N,T,1) fp32

    // ws layout: [0, 12288) tabs (N*12 u32)
    unsigned* tabs = (unsigned*)d_ws;

    hipLaunchKernelGGL(k_disc, dim3((P_ * N_ + 255) / 256), dim3(256), 0, stream,
                       patterns, tabs);
    hipLaunchKernelGGL(k_mega, dim3(T_ / 1024, B_), dim3(256), 0, stream,
                       input_, tabs, out);
}

// Round 8
// 90.300 us; speedup vs baseline: 1.4949x; 1.2226x over previous
//
#include <hip/hip_runtime.h>

// Problem constants (from reference)
#define B_ 32
#define C_ 32
#define T_ 8192
#define N_ 256
#define P_ 6
#define TV_ (T_ - P_ + 1)   // valid conv length = 8187

// ---------------------------------------------------------------------------
// Kernel 0 (verbatim r5): discretize patterns -> byte-SIMD match tables.
// tabs[n][12]: dwords 0..5 = xs[p] (XOR splat), 6..11 = om[p] (active mask).
//   pc==0 (col sum<=0): don't-care -> om=0
//   pc==1 (unique argmax): xs=req*0x01010101, om=0x80808080
//   pc>=2 (tie): never matches   -> xs=0x7F7F7F7F, om=0x80808080
// ---------------------------------------------------------------------------
__global__ void k_disc(const float* __restrict__ pat, unsigned* __restrict__ tabs) {
    int tid = blockIdx.x * blockDim.x + threadIdx.x;
    if (tid >= P_ * N_) return;
    int p = tid / N_;
    int n = tid - p * N_;
    float maxv = -3.402823466e+38f;
    float sum = 0.0f;
    unsigned mask = 0u;
    #pragma unroll
    for (int c = 0; c < C_; ++c) {
        float v = pat[((size_t)c * P_ + p) * N_ + n];
        sum += v;
        if (v > maxv) { maxv = v; mask = (1u << c); }
        else if (v == maxv) { mask |= (1u << c); }
    }
    if (!(sum > 0.0f)) mask = 0u;
    int pc = __popc(mask);
    unsigned req = (unsigned)(__ffs((int)mask) - 1);
    unsigned xs = (pc == 1) ? req * 0x01010101u : 0x7F7F7F7Fu;
    unsigned om = (pc == 0) ? 0u : 0x80808080u;
    tabs[n * 12 + p]     = xs;
    tabs[n * 12 + 6 + p] = om;
}

// ---------------------------------------------------------------------------
// k_one: fused decode+match at r5's PROVEN 2048-block geometry.
// Grid (tc=8, ng=8, b=32); each block decodes the (tc,b) chars chunk into LDS
// (8x ng-redundant, but linear id = tc + 8*(ng+8b) -> XCD = tc, so all 8
// duplicates hit the same XCD's L2: ~7/8 of decode reads are L2 hits), then
// runs the r5 32-n store loop (8 blocks/CU -> the TLP phase 2 needs; r7
// proved 1 block/CU is 3x too slow).
// ---------------------------------------------------------------------------
__global__ void k_one(const float* __restrict__ inp,
                      const unsigned* __restrict__ tabs,
                      float* __restrict__ out) {
    __shared__ unsigned s32[258];         // 1024 chars + 8 halo bytes
    int tc  = blockIdx.x;                 // 0..7
    int ng  = blockIdx.y;                 // 0..7  (group of 32 n)
    int b   = blockIdx.z;                 // 0..31
    int tid = threadIdx.x;
    int t0  = tc << 10;
    int tb  = t0 + (tid << 2);

    // ---- phase 1: one-hot decode, 4 consecutive t per thread -> LDS ----
    {
        const float* base = inp + (size_t)b * C_ * T_ + tb;
        float ax = 0.f, ay = 0.f, az = 0.f, aw = 0.f;
        #pragma unroll
        for (int c = 0; c < C_; ++c) {
            float4 v = *(const float4*)(base + (size_t)c * T_);
            float fc = (float)c;
            ax += fc * v.x; ay += fc * v.y; az += fc * v.z; aw += fc * v.w;
        }
        s32[tid] = ((unsigned)(ax + 0.5f))
                 | ((unsigned)(ay + 0.5f) << 8)
                 | ((unsigned)(az + 0.5f) << 16)
                 | ((unsigned)(aw + 0.5f) << 24);
        if (tid < 2) {                    // 8 halo t's (t0+1024 .. t0+1031)
            unsigned w = 0u;
            if (tc < 7) {                 // tc==7: halo OOB -> zeros; pad region anyway
                const float* hb = inp + (size_t)b * C_ * T_ + (t0 + 1024 + (tid << 2));
                float hx = 0.f, hy = 0.f, hz = 0.f, hw = 0.f;
                #pragma unroll
                for (int c = 0; c < C_; ++c) {
                    float4 v = *(const float4*)(hb + (size_t)c * T_);
                    float fc = (float)c;
                    hx += fc * v.x; hy += fc * v.y; hz += fc * v.z; hw += fc * v.w;
                }
                w = ((unsigned)(hx + 0.5f))
                  | ((unsigned)(hy + 0.5f) << 8)
                  | ((unsigned)(hz + 0.5f) << 16)
                  | ((unsigned)(hw + 0.5f) << 24);
            }
            s32[256 + tid] = w;
        }
    }
    __syncthreads();

    // ---- phase 2: verbatim r5 match loop over this block's 32 n ----
    unsigned w0 = s32[tid], w1 = s32[tid + 1], w2 = s32[tid + 2];
    unsigned cw0 = w0;
    unsigned cw1 = __builtin_amdgcn_alignbyte(w1, w0, 1);
    unsigned cw2 = __builtin_amdgcn_alignbyte(w1, w0, 2);
    unsigned cw3 = __builtin_amdgcn_alignbyte(w1, w0, 3);
    unsigned cw4 = w1;
    unsigned cw5 = __builtin_amdgcn_alignbyte(w2, w1, 1);

    int n0 = ng << 5;
    const uint4* tp = (const uint4*)tabs + (size_t)n0 * 3;
    float* obase = out + ((size_t)(b * N_ + n0)) * T_ + tb;
    bool tail = (tc == 7) && (tb + 3 >= TV_);

    #pragma unroll 4
    for (int g = 0; g < 32; ++g) {
        uint4 A  = tp[g * 3 + 0];         // xs0..xs3   (uniform -> s_load)
        uint4 Bv = tp[g * 3 + 1];         // xs4, xs5, om0, om1
        uint4 Cv = tp[g * 3 + 2];         // om2..om5

        unsigned orv;
        orv  = ((cw0 ^ A.x)  + 0x7F7F7F7FU) & Bv.z;
        orv |= ((cw1 ^ A.y)  + 0x7F7F7F7FU) & Bv.w;   // v_and_or_b32
        orv |= ((cw2 ^ A.z)  + 0x7F7F7F7FU) & Cv.x;
        orv |= ((cw3 ^ A.w)  + 0x7F7F7F7FU) & Cv.y;
        orv |= ((cw4 ^ Bv.x) + 0x7F7F7F7FU) & Cv.z;
        orv |= ((cw5 ^ Bv.y) + 0x7F7F7F7FU) & Cv.w;

        float res[4];
        #pragma unroll
        for (int j = 0; j < 4; ++j)
            res[j] = (orv & (0x80u << (8 * j))) ? 0.0f : 1.0f;

        if (tail) {                       // only last chunk's tail lanes
            unsigned act = Bv.z | Bv.w | Cv.x | Cv.y | Cv.z | Cv.w;
            float padf = (act == 0u) ? 1.0f : 0.0f;  // psum==0: pad matches
            #pragma unroll
            for (int j = 0; j < 4; ++j)
                if (tb + j >= TV_) res[j] = padf;
        }

        float4 r; r.x = res[0]; r.y = res[1]; r.z = res[2]; r.w = res[3];
        *(float4*)(obase + (size_t)g * T_) = r;
    }
}

// ---------------------------------------------------------------------------
extern "C" void kernel_launch(void* const* d_in, const int* in_sizes, int n_in,
                              void* d_out, int out_size, void* d_ws, size_t ws_size,
                              hipStream_t stream) {
    const float* input_   = (const float*)d_in[0];   // (B,C,T,1) one-hot fp32
    const float* patterns = (const float*)d_in[1];   // (C,P,1,N) fp32
    float* out = (float*)d_out;                      // (B,N,T,1) fp32

    // ws layout: [0, 12288) tabs (N*12 u32)
    unsigned* tabs = (unsigned*)d_ws;

    hipLaunchKernelGGL(k_disc, dim3((P_ * N_ + 255) / 256), dim3(256), 0, stream,
                       patterns, tabs);
    hipLaunchKernelGGL(k_one, dim3(T_ / 1024, N_ / 32, B_), dim3(256), 0, stream,
                       input_, tabs, out);
}

// Round 9
// 69.558 us; speedup vs baseline: 1.9407x; 1.2982x over previous
//
#include <hip/hip_runtime.h>

// Problem constants (from reference)
#define B_ 32
#define C_ 32
#define T_ 8192
#define N_ 256
#define P_ 6
#define TV_ (T_ - P_ + 1)   // valid conv length = 8187

// ---------------------------------------------------------------------------
// Kernel 0 (verbatim r5): discretize patterns -> byte-SIMD match tables.
// tabs[n][12]: dwords 0..5 = xs[p] (XOR splat), 6..11 = om[p] (active mask).
//   pc==0 (col sum<=0): don't-care -> om=0
//   pc==1 (unique argmax): xs=req*0x01010101, om=0x80808080
//   pc>=2 (tie): never matches   -> xs=0x7F7F7F7F, om=0x80808080
// ---------------------------------------------------------------------------
__global__ void k_disc(const float* __restrict__ pat, unsigned* __restrict__ tabs) {
    int tid = blockIdx.x * blockDim.x + threadIdx.x;
    if (tid >= P_ * N_) return;
    int p = tid / N_;
    int n = tid - p * N_;
    float maxv = -3.402823466e+38f;
    float sum = 0.0f;
    unsigned mask = 0u;
    #pragma unroll
    for (int c = 0; c < C_; ++c) {
        float v = pat[((size_t)c * P_ + p) * N_ + n];
        sum += v;
        if (v > maxv) { maxv = v; mask = (1u << c); }
        else if (v == maxv) { mask |= (1u << c); }
    }
    if (!(sum > 0.0f)) mask = 0u;
    int pc = __popc(mask);
    unsigned req = (unsigned)(__ffs((int)mask) - 1);
    unsigned xs = (pc == 1) ? req * 0x01010101u : 0x7F7F7F7Fu;
    unsigned om = (pc == 0) ? 0u : 0x80808080u;
    tabs[n * 12 + p]     = xs;
    tabs[n * 12 + 6 + p] = om;
}

// ---------------------------------------------------------------------------
// Kernel 1 REWRITTEN for TLP: decode one-hot -> chars[B][T] (u8 packed u32).
// Old: 256 blocks (1 wave/SIMD), 32 loads/thread -> latency-bound, ~1.1 TB/s.
// New: 1024 blocks (16 waves/CU); thread = (t-quad q, c-group cg of 8 c),
// 8 float4 loads + partial sum; LDS reduce over the 4 c-groups; tid<64 packs.
// ---------------------------------------------------------------------------
__global__ void k_chars(const float* __restrict__ inp, unsigned* __restrict__ chars32) {
    __shared__ float4 s_part[256];        // 4 KB
    int bx  = blockIdx.x;                 // [0, B * T/256) = 1024
    int b   = bx >> 5;                    // 32 chunks per batch
    int t0  = (bx & 31) << 8;             // 256-t chunk
    int tid = threadIdx.x;
    int q   = tid & 63;                   // t-quad within chunk (64 quads)
    int cg  = tid >> 6;                   // c-group 0..3 (8 c each)
    int t   = t0 + (q << 2);

    const float* base = inp + (size_t)b * C_ * T_ + t;
    float ax = 0.f, ay = 0.f, az = 0.f, aw = 0.f;
    #pragma unroll
    for (int i = 0; i < 8; ++i) {
        int c = (cg << 3) + i;
        float4 v = *(const float4*)(base + (size_t)c * T_);
        float fc = (float)c;
        ax += fc * v.x; ay += fc * v.y; az += fc * v.z; aw += fc * v.w;
    }
    s_part[tid] = make_float4(ax, ay, az, aw);
    __syncthreads();

    if (tid < 64) {
        float4 p0 = s_part[tid];
        float4 p1 = s_part[tid + 64];
        float4 p2 = s_part[tid + 128];
        float4 p3 = s_part[tid + 192];
        float sx = p0.x + p1.x + p2.x + p3.x;
        float sy = p0.y + p1.y + p2.y + p3.y;
        float sz = p0.z + p1.z + p2.z + p3.z;
        float sw = p0.w + p1.w + p2.w + p3.w;
        unsigned w = ((unsigned)(sx + 0.5f))
                   | ((unsigned)(sy + 0.5f) << 8)
                   | ((unsigned)(sz + 0.5f) << 16)
                   | ((unsigned)(sw + 0.5f) << 24);
        chars32[(((size_t)b * T_ + t0) >> 2) + tid] = w;
    }
}

// ---------------------------------------------------------------------------
// Kernel 2 (verbatim r5, measured 33.2us = write roofline): grid (8,8,32),
// LDS chars staging, byte-SIMD match, 32-n loop, one float4 store/thread/n.
// ---------------------------------------------------------------------------
__global__ void k_final(const unsigned char* __restrict__ chars,
                        const unsigned* __restrict__ tabs,
                        float* __restrict__ out) {
    __shared__ unsigned s32[258];         // 1024 chars + 8 halo bytes
    int tc  = blockIdx.x;                 // 0..7
    int ng  = blockIdx.y;                 // 0..7  (group of 32 n)
    int b   = blockIdx.z;                 // 0..31
    int tid = threadIdx.x;
    int t0  = tc << 10;
    int tb  = t0 + (tid << 2);

    const unsigned* csrc = (const unsigned*)(chars + (size_t)b * T_ + t0);
    s32[tid] = csrc[tid];
    if (tid < 2) {
        unsigned v = 0u;
        int gt = t0 + 1024 + tid * 4;     // byte index into chars[b][*]
        if (gt < T_) v = csrc[256 + tid];
        s32[256 + tid] = v;
    }
    __syncthreads();

    unsigned w0 = s32[tid], w1 = s32[tid + 1], w2 = s32[tid + 2];
    unsigned cw0 = w0;
    unsigned cw1 = __builtin_amdgcn_alignbyte(w1, w0, 1);
    unsigned cw2 = __builtin_amdgcn_alignbyte(w1, w0, 2);
    unsigned cw3 = __builtin_amdgcn_alignbyte(w1, w0, 3);
    unsigned cw4 = w1;
    unsigned cw5 = __builtin_amdgcn_alignbyte(w2, w1, 1);

    int n0 = ng << 5;
    const uint4* tp = (const uint4*)tabs + (size_t)n0 * 3;
    float* obase = out + ((size_t)(b * N_ + n0)) * T_ + tb;
    bool tail = (tc == 7) && (tb + 3 >= TV_);

    #pragma unroll 4
    for (int g = 0; g < 32; ++g) {
        uint4 A  = tp[g * 3 + 0];         // xs0..xs3   (uniform -> s_load)
        uint4 Bv = tp[g * 3 + 1];         // xs4, xs5, om0, om1
        uint4 Cv = tp[g * 3 + 2];         // om2..om5

        unsigned orv;
        orv  = ((cw0 ^ A.x)  + 0x7F7F7F7FU) & Bv.z;
        orv |= ((cw1 ^ A.y)  + 0x7F7F7F7FU) & Bv.w;   // v_and_or_b32
        orv |= ((cw2 ^ A.z)  + 0x7F7F7F7FU) & Cv.x;
        orv |= ((cw3 ^ A.w)  + 0x7F7F7F7FU) & Cv.y;
        orv |= ((cw4 ^ Bv.x) + 0x7F7F7F7FU) & Cv.z;
        orv |= ((cw5 ^ Bv.y) + 0x7F7F7F7FU) & Cv.w;

        float res[4];
        #pragma unroll
        for (int j = 0; j < 4; ++j)
            res[j] = (orv & (0x80u << (8 * j))) ? 0.0f : 1.0f;

        if (tail) {                       // only last chunk's tail lanes
            unsigned act = Bv.z | Bv.w | Cv.x | Cv.y | Cv.z | Cv.w;
            float padf = (act == 0u) ? 1.0f : 0.0f;  // psum==0: pad matches
            #pragma unroll
            for (int j = 0; j < 4; ++j)
                if (tb + j >= TV_) res[j] = padf;
        }

        float4 r; r.x = res[0]; r.y = res[1]; r.z = res[2]; r.w = res[3];
        *(float4*)(obase + (size_t)g * T_) = r;
    }
}

// ---------------------------------------------------------------------------
extern "C" void kernel_launch(void* const* d_in, const int* in_sizes, int n_in,
                              void* d_out, int out_size, void* d_ws, size_t ws_size,
                              hipStream_t stream) {
    const float* input_   = (const float*)d_in[0];   // (B,C,T,1) one-hot fp32
    const float* patterns = (const float*)d_in[1];   // (C,P,1,N) fp32
    float* out = (float*)d_out;                      // (B,N,T,1) fp32

    // ws layout: [0, 12288) tabs (N*12 u32); [16384, 16384+256K) chars u8
    unsigned*      tabs  = (unsigned*)d_ws;
    unsigned char* chars = (unsigned char*)d_ws + 16384;

    hipLaunchKernelGGL(k_disc, dim3((P_ * N_ + 255) / 256), dim3(256), 0, stream,
                       patterns, tabs);
    hipLaunchKernelGGL(k_chars, dim3(B_ * (T_ / 256)), dim3(256), 0, stream,
                       input_, (unsigned*)chars);
    hipLaunchKernelGGL(k_final, dim3(T_ / 1024, N_ / 32, B_), dim3(256), 0, stream,
                       chars, tabs, out);
}